// Round 6
// baseline (3504.168 us; speedup 1.0000x reference)
//
#include <hip/hip_runtime.h>
#include <stdint.h>

#define HH 128
#define WW 128
#define NIMG 32
#define CH 16
#define TILE 16
#define LW 20            // 16 + 2*2 halo
#define LA (LW * LW)     // 400 floats per channel plane
#define NUM_ITER 30
#define THR 0.1f
#define HWSZ (HH * WW)

typedef __attribute__((ext_vector_type(8))) short frag;      // 8 bf16 = A/B operand
typedef __attribute__((ext_vector_type(4))) float f32x4;     // C/D
typedef __attribute__((ext_vector_type(4))) unsigned int u32x4;
typedef __attribute__((ext_vector_type(2))) unsigned int u32x2;
#define MFMA16(a, b, c) __builtin_amdgcn_mfma_f32_16x16x32_bf16(a, b, c, 0, 0, 0)
// Compiler memory fence: stops TBAA-based reordering of LDS uint-stores vs
// frag-loads (R5 failure: layer-2 B-loads hoisted above H write-back).
#define MEMFENCE asm volatile("" ::: "memory")

// Load an MFMA frag from LDS through uint typing (aliases with uint stores).
__device__ __forceinline__ frag ldsfrag(const unsigned int* p) {
    u32x4 v = *(const u32x4*)p;
    return __builtin_bit_cast(frag, v);
}

// 3-way bf16 split: x ~= s1 + s2 + s3, dropped residual <= ~2^-23|x|.
// Level 1 RNE (carry trick), levels 2/3 truncate. Outputs hold bf16 bits in TOP 16.
__device__ __forceinline__ void split3(float x, unsigned& s1, unsigned& s2, unsigned& s3) {
    unsigned u = __float_as_uint(x);
    unsigned r = u + 0x7FFF + ((u >> 16) & 1);
    s1 = r & 0xFFFF0000u;
    float d1 = x - __uint_as_float(s1);
    s2 = __float_as_uint(d1) & 0xFFFF0000u;
    float d2 = d1 - __uint_as_float(s2);
    s3 = __float_as_uint(d2) & 0xFFFF0000u;
}
__device__ __forceinline__ unsigned pack2(unsigned lo_hi16, unsigned hi_hi16) {
    return (lo_hi16 >> 16) | (hi_hi16 & 0xFFFF0000u);
}

// ---------------- init: build 16-ch cell state from 10-ch input ----------------
__global__ __launch_bounds__(256) void init_kernel(const float* __restrict__ inp,
                                                   float* __restrict__ cell) {
    int i = blockIdx.x * 256 + threadIdx.x;
    if (i >= NIMG * CH * HWSZ) return;
    int hw = i % HWSZ;
    int c  = (i / HWSZ) % CH;
    int n  = i / (CH * HWSZ);
    float v;
    if (c == 0)       v = 1.0f - inp[(n * 10 + 0) * HWSZ + hw];
    else if (c <= 10) v = inp[(n * 10 + (c - 1)) * HWSZ + hw];
    else              v = 0.0f;
    cell[i] = v;
}

// ---------------- prep: 3-way split weights into MFMA-friendly u16 arrays ------
// w1s: [3][48][64] (k padded 48..63 = 0), w2s: [3][16][64]
__global__ __launch_bounds__(256) void prep_weights(const float* __restrict__ w1,
                                                    const float* __restrict__ w2,
                                                    unsigned short* __restrict__ w1s,
                                                    unsigned short* __restrict__ w2s) {
    int i = blockIdx.x * 256 + threadIdx.x;     // 64 rows x 64 k
    if (i >= 64 * 64) return;
    int row = i >> 6, k = i & 63;
    float x = 0.0f;
    if (k < 48) x = (row < 48) ? w1[row * 48 + k] : w2[(row - 48) * 48 + k];
    unsigned s1, s2, s3;
    split3(x, s1, s2, s3);
    if (row < 48) {
        w1s[0 * 3072 + row * 64 + k] = (unsigned short)(s1 >> 16);
        w1s[1 * 3072 + row * 64 + k] = (unsigned short)(s2 >> 16);
        w1s[2 * 3072 + row * 64 + k] = (unsigned short)(s3 >> 16);
    } else {
        int r = row - 48;
        w2s[0 * 1024 + r * 64 + k] = (unsigned short)(s1 >> 16);
        w2s[1 * 1024 + r * 64 + k] = (unsigned short)(s2 >> 16);
        w2s[2 * 1024 + r * 64 + k] = (unsigned short)(s3 >> 16);
    }
}

// perception: p[0..15]=center, p[16..31]=sobel-x, p[32..47]=sobel-y
__device__ __forceinline__ void perception_at(const float* cs, int base, float* p) {
#pragma unroll
    for (int c = 0; c < CH; ++c) {
        const float* cc = cs + c * LA;
        float c00 = cc[base - LW - 1], c01 = cc[base - LW], c02 = cc[base - LW + 1];
        float c10 = cc[base - 1],      c11 = cc[base],      c12 = cc[base + 1];
        float c20 = cc[base + LW - 1], c21 = cc[base + LW], c22 = cc[base + LW + 1];
        p[c]      = c11;
        p[16 + c] = (c02 - c00 + 2.0f * (c12 - c10) + c22 - c20) * 0.125f;
        p[32 + c] = (c20 - c00 + 2.0f * (c21 - c01) + c22 - c02) * 0.125f;
    }
}

// ---------------- one fused CA step (MFMA matmuls) ----------------
__global__ __launch_bounds__(256, 3) void step_kernel(
    const float* __restrict__ cin, float* __restrict__ cout,
    const uint8_t* __restrict__ pre_in, uint8_t* __restrict__ pre_out,
    const unsigned short* __restrict__ w1s, const unsigned short* __restrict__ w2s,
    int gate) {

    __shared__ __align__(16) float cs[CH * LA];        // 25600 B
    __shared__ __align__(16) unsigned int ph[4 * 3 * 16 * 36];  // 27648 B; gm aliases
    float* gm = (float*)ph;   // used only in phases B/C (before barrier)

    const int tid = threadIdx.x;
    const int tx = tid & 15, ty = tid >> 4;
    const int bx = blockIdx.x * TILE, by = blockIdx.y * TILE;
    const int n = blockIdx.z;
    const float* cbase = cin + (size_t)n * CH * HWSZ;
    const uint8_t* pbase = pre_in + (size_t)n * HWSZ;

    // ---- hoisted coords: full 20x20 positions (ch0), two per thread ----
    const int lyA = tid / 20, lxA = tid % 20;
    const int gyA = by + lyA - 2, gxA = bx + lxA - 2;
    const bool okA = ((unsigned)gyA < HH) && ((unsigned)gxA < WW);
    const int offA = gyA * WW + gxA;

    const int rB = tid + 256;                  // valid when tid < 144
    const int lyB = rB / 20, lxB = rB % 20;
    const int gyB = by + lyB - 2, gxB = bx + lxB - 2;
    const bool okB = ((unsigned)gyB < HH) && ((unsigned)gxB < WW);
    const int offB = gyB * WW + gxB;

    // ---- hoisted coords: 18x18 region positions, two per thread ----
    const int j0 = tid;
    const int jy0 = j0 / 18, jx0 = j0 % 18;
    const int gy0 = by + jy0 - 1, gx0 = bx + jx0 - 1;
    const bool ok0 = ((unsigned)gy0 < HH) && ((unsigned)gx0 < WW);
    const int goff0 = gy0 * WW + gx0;
    const int lpos0 = (jy0 + 1) * LW + (jx0 + 1);

    const int j1 = tid + 256;                  // valid when tid < 68
    const int jy1 = j1 / 18, jx1 = j1 % 18;
    const int gy1 = by + jy1 - 1, gx1 = bx + jx1 - 1;
    const bool ok1 = ((unsigned)gy1 < HH) && ((unsigned)gx1 < WW);
    const int goff1 = gy1 * WW + gx1;
    const int lpos1 = (jy1 + 1) * LW + (jx1 + 1);

    // ---- A: stage raw ch0 (full 20x20, zero-fill OOB) ----
    cs[tid] = okA ? cbase[offA] : 0.0f;
    if (tid < 144) cs[rB] = okB ? cbase[offB] : 0.0f;
    __syncthreads();

    // ---- B: gate mask gm over 18x18 ----
    {
        float pm = -1e30f;
#pragma unroll
        for (int dy = -1; dy <= 1; ++dy)
#pragma unroll
            for (int dx = -1; dx <= 1; ++dx)
                pm = fmaxf(pm, cs[lpos0 + dy * LW + dx]);
        float mval = 1.0f;
        if (gate) {
            int pv = ok0 ? pbase[goff0] : 0;
            mval = (pv && pm > THR) ? 1.0f : 0.0f;
        }
        gm[j0] = mval;
    }
    if (tid < 68) {
        float pm = -1e30f;
#pragma unroll
        for (int dy = -1; dy <= 1; ++dy)
#pragma unroll
            for (int dx = -1; dx <= 1; ++dx)
                pm = fmaxf(pm, cs[lpos1 + dy * LW + dx]);
        float mval = 1.0f;
        if (gate) {
            int pv = ok1 ? pbase[goff1] : 0;
            mval = (pv && pm > THR) ? 1.0f : 0.0f;
        }
        gm[j1] = mval;
    }
    __syncthreads();

    // ---- C: gate ch0 in LDS; stage ch1..15 (18x18) with gate folded in ----
    {
        const float g = gm[j0];
        cs[lpos0] *= g;
        const float* gp = cbase + goff0;
#pragma unroll
        for (int c = 1; c < CH; ++c)
            cs[c * LA + lpos0] = (ok0 ? gp[c * HWSZ] : 0.0f) * g;
    }
    if (tid < 68) {
        const float g = gm[j1];
        cs[lpos1] *= g;
        const float* gp = cbase + goff1;
#pragma unroll
        for (int c = 1; c < CH; ++c)
            cs[c * LA + lpos1] = (ok1 ? gp[c * HWSZ] : 0.0f) * g;
    }
    __syncthreads();
    // (gm is dead from here; ph may be overwritten in phase E)

    // ---- D: pre(i) bits + perception + 3-way split/pack ----
    const int base = (ty + 2) * LW + (tx + 2);
    float pm = -1e30f;
#pragma unroll
    for (int dy = -1; dy <= 1; ++dy)
#pragma unroll
        for (int dx = -1; dx <= 1; ++dx)
            pm = fmaxf(pm, cs[base + dy * LW + dx]);
    pre_out[(size_t)n * HWSZ + (size_t)(by + ty) * WW + (bx + tx)] = (pm > THR) ? 1 : 0;

    float p[48];
    perception_at(cs, base, p);

    unsigned pw0[24], pw1[24], pw2[24];
#pragma unroll
    for (int w = 0; w < 24; ++w) {
        unsigned a1, a2, a3, b1, b2, b3;
        split3(p[2 * w],     a1, a2, a3);
        split3(p[2 * w + 1], b1, b2, b3);
        pw0[w] = pack2(a1, b1);
        pw1[w] = pack2(a2, b2);
        pw2[w] = pack2(a3, b3);
    }

    // ---- E: MFMA tile loop ----
    const int lane = tid & 63;
    const int px = lane & 15;       // B-frag col / D column
    const int q  = lane >> 4;       // quad
    const int wv = tid >> 6;        // wave in block
    unsigned int* phw = ph + wv * 1728;   // [3 splits][16 rows][36 words]

    frag a1h[3][2];                 // held w1 split-1 A-frags
#pragma unroll
    for (int ot = 0; ot < 3; ++ot)
#pragma unroll
        for (int kc = 0; kc < 2; ++kc)
            a1h[ot][kc] = *(const frag*)(w1s + (ot * 16 + px) * 64 + kc * 32 + q * 8);

    float* obase = cout + (size_t)n * CH * HWSZ;

    for (int t = 0; t < 4; ++t) {
        // quad t publishes its row's packed perception splits (+ zero k-pad)
        if (q == t) {
#pragma unroll
            for (int s = 0; s < 3; ++s) {
                unsigned int* row = phw + s * 576 + px * 36;
                const unsigned* pws = (s == 0) ? pw0 : (s == 1) ? pw1 : pw2;
#pragma unroll
                for (int i = 0; i < 6; ++i) {
                    u32x4 v = { pws[4 * i], pws[4 * i + 1], pws[4 * i + 2], pws[4 * i + 3] };
                    *(u32x4*)(row + 4 * i) = v;
                }
                u32x4 z = { 0, 0, 0, 0 };
                *(u32x4*)(row + 24) = z;
                *(u32x4*)(row + 28) = z;
            }
        }
        MEMFENCE;   // publish must precede B-frag loads (same-wave LDS is in-order in HW)

        // layer 1: H[48 x 16px] = W1 * P
        f32x4 c1[3] = { {0,0,0,0}, {0,0,0,0}, {0,0,0,0} };
#pragma unroll
        for (int kc = 0; kc < 2; ++kc) {
            frag b1 = ldsfrag(phw + 0 * 576 + px * 36 + kc * 16 + q * 4);
            frag b2 = ldsfrag(phw + 1 * 576 + px * 36 + kc * 16 + q * 4);
            frag b3 = ldsfrag(phw + 2 * 576 + px * 36 + kc * 16 + q * 4);
#pragma unroll
            for (int ot = 0; ot < 3; ++ot) {
                frag a2 = *(const frag*)(w1s + 3072 + (ot * 16 + px) * 64 + kc * 32 + q * 8);
                frag a3 = *(const frag*)(w1s + 6144 + (ot * 16 + px) * 64 + kc * 32 + q * 8);
                c1[ot] = MFMA16(a1h[ot][kc], b1, c1[ot]);
                c1[ot] = MFMA16(a1h[ot][kc], b2, c1[ot]);
                c1[ot] = MFMA16(a2,          b1, c1[ot]);
                c1[ot] = MFMA16(a1h[ot][kc], b3, c1[ot]);
                c1[ot] = MFMA16(a2,          b2, c1[ot]);
                c1[ot] = MFMA16(a3,          b1, c1[ot]);
            }
        }
        MEMFENCE;   // B-frag loads of P must complete before H overwrite below

        // relu + split + write H into same buffer (words 0..23; zeros 24..31 persist)
#pragma unroll
        for (int ot = 0; ot < 3; ++ot) {
            unsigned s1b[4], s2b[4], s3b[4];
#pragma unroll
            for (int r = 0; r < 4; ++r) {
                float h = fmaxf(c1[ot][r], 0.0f);
                split3(h, s1b[r], s2b[r], s3b[r]);
            }
            u32x2 v0 = { pack2(s1b[0], s1b[1]), pack2(s1b[2], s1b[3]) };
            *(u32x2*)(phw + 0 * 576 + px * 36 + ot * 8 + q * 2) = v0;
            u32x2 v1 = { pack2(s2b[0], s2b[1]), pack2(s2b[2], s2b[3]) };
            *(u32x2*)(phw + 1 * 576 + px * 36 + ot * 8 + q * 2) = v1;
            u32x2 v2 = { pack2(s3b[0], s3b[1]), pack2(s3b[2], s3b[3]) };
            *(u32x2*)(phw + 2 * 576 + px * 36 + ot * 8 + q * 2) = v2;
        }
        MEMFENCE;   // H stores must precede layer-2 B-frag loads (R5 bug)

        // layer 2: cur[16ch x 16px] = W2 * relu(H) + cell   (C-init = residual)
        const int rloc = 4 * wv + t;
        f32x4 c2;
#pragma unroll
        for (int r = 0; r < 4; ++r)
            c2[r] = cs[(q * 4 + r) * LA + (rloc + 2) * LW + (px + 2)];
#pragma unroll
        for (int kc = 0; kc < 2; ++kc) {
            frag b1 = ldsfrag(phw + 0 * 576 + px * 36 + kc * 16 + q * 4);
            frag b2 = ldsfrag(phw + 1 * 576 + px * 36 + kc * 16 + q * 4);
            frag b3 = ldsfrag(phw + 2 * 576 + px * 36 + kc * 16 + q * 4);
            frag wa1 = *(const frag*)(w2s +    0 + px * 64 + kc * 32 + q * 8);
            frag wa2 = *(const frag*)(w2s + 1024 + px * 64 + kc * 32 + q * 8);
            frag wa3 = *(const frag*)(w2s + 2048 + px * 64 + kc * 32 + q * 8);
            c2 = MFMA16(wa1, b1, c2);
            c2 = MFMA16(wa1, b2, c2);
            c2 = MFMA16(wa2, b1, c2);
            c2 = MFMA16(wa1, b3, c2);
            c2 = MFMA16(wa2, b2, c2);
            c2 = MFMA16(wa3, b1, c2);
        }
        MEMFENCE;   // layer-2 B loads must precede next iteration's publish (WAR)

        // store ungated cur: lanes cover 16 px contiguous per channel row
        float* ob = obase + (size_t)(by + rloc) * WW + bx + px;
#pragma unroll
        for (int r = 0; r < 4; ++r)
            ob[(size_t)(q * 4 + r) * HWSZ] = c2[r];
    }
}

// ---------------- final: apply gate(30), emit channels 1..10 ----------------
__global__ __launch_bounds__(256) void final_kernel(
    const float* __restrict__ cur, const uint8_t* __restrict__ pre,
    float* __restrict__ out) {
    int i = blockIdx.x * 256 + threadIdx.x;
    if (i >= NIMG * HWSZ) return;
    int x = i % WW, y = (i / WW) % HH, n = i / HWSZ;
    const float* c0 = cur + (size_t)n * CH * HWSZ;
    float pm = -1e30f;
    for (int dy = -1; dy <= 1; ++dy) {
        int yy = y + dy;
        if ((unsigned)yy >= HH) continue;
        for (int dx = -1; dx <= 1; ++dx) {
            int xx = x + dx;
            if ((unsigned)xx >= WW) continue;
            pm = fmaxf(pm, c0[yy * WW + xx]);
        }
    }
    const bool alive = pre[i] && (pm > THR);
    float* ob = out + (size_t)n * 10 * HWSZ + y * WW + x;
#pragma unroll
    for (int k = 1; k <= 10; ++k)
        ob[(k - 1) * HWSZ] = alive ? c0[k * HWSZ + y * WW + x] : 0.0f;
}

extern "C" void kernel_launch(void* const* d_in, const int* in_sizes, int n_in,
                              void* d_out, int out_size, void* d_ws, size_t ws_size,
                              hipStream_t stream) {
    const float* inp = (const float*)d_in[0];
    const float* w1  = (const float*)d_in[1];
    const float* w2  = (const float*)d_in[2];
    float* out = (float*)d_out;

    const size_t SE = (size_t)NIMG * CH * HWSZ;    // 8,388,608 floats
    float* bufA = (float*)d_ws;
    float* bufB = bufA + SE;
    uint8_t* bitsA = (uint8_t*)(bufB + SE);
    uint8_t* bitsB = bitsA + (size_t)NIMG * HWSZ;
    unsigned short* w1s = (unsigned short*)(bitsB + (size_t)NIMG * HWSZ); // [3][48][64]
    unsigned short* w2s = w1s + 3 * 48 * 64;                              // [3][16][64]

    init_kernel<<<((int)SE + 255) / 256, 256, 0, stream>>>(inp, bufA);
    prep_weights<<<16, 256, 0, stream>>>(w1, w2, w1s, w2s);

    dim3 grid(WW / TILE, HH / TILE, NIMG);
    float* src = bufA;
    float* dst = bufB;
    uint8_t* pin = bitsB;   // unused on first iter (gate=0)
    uint8_t* pout = bitsA;
    for (int it = 0; it < NUM_ITER; ++it) {
        step_kernel<<<grid, 256, 0, stream>>>(src, dst, pin, pout, w1s, w2s,
                                              it == 0 ? 0 : 1);
        float* t = src; src = dst; dst = t;
        uint8_t* tb = pin; pin = pout; pout = tb;
    }
    // after loop: src = cur(30), pin = pre(30) bits
    final_kernel<<<(NIMG * HWSZ + 255) / 256, 256, 0, stream>>>(src, pin, out);
}

// Round 7
// 3421.806 us; speedup vs baseline: 1.0241x; 1.0241x over previous
//
#include <hip/hip_runtime.h>
#include <stdint.h>

#define HH 128
#define WW 128
#define NIMG 32
#define CH 16
#define TILE 16
#define LW 20            // 16 + 2*2 halo
#define LA (LW * LW)     // 400 floats per channel plane
#define NUM_ITER 30
#define THR 0.1f
#define HWSZ (HH * WW)

typedef __attribute__((ext_vector_type(8))) short frag;      // 8 bf16 = A/B operand
typedef __attribute__((ext_vector_type(4))) float f32x4;     // C/D
typedef __attribute__((ext_vector_type(4))) unsigned int u32x4;
typedef __attribute__((ext_vector_type(2))) unsigned int u32x2;
#define MFMA16(a, b, c) __builtin_amdgcn_mfma_f32_16x16x32_bf16(a, b, c, 0, 0, 0)
// Compiler memory fence: stops TBAA-based reordering of LDS uint-stores vs
// frag-loads (R5 failure: layer-2 B-loads hoisted above H write-back).
#define MEMFENCE asm volatile("" ::: "memory")

// Load an MFMA frag from LDS through uint typing (aliases with uint stores).
__device__ __forceinline__ frag ldsfrag(const unsigned int* p) {
    u32x4 v = *(const u32x4*)p;
    return __builtin_bit_cast(frag, v);
}

// 3-way bf16 split: x ~= s1 + s2 + s3, dropped residual <= ~2^-23|x|.
// Level 1 RNE (carry trick), levels 2/3 truncate. Outputs hold bf16 bits in TOP 16.
__device__ __forceinline__ void split3(float x, unsigned& s1, unsigned& s2, unsigned& s3) {
    unsigned u = __float_as_uint(x);
    unsigned r = u + 0x7FFF + ((u >> 16) & 1);
    s1 = r & 0xFFFF0000u;
    float d1 = x - __uint_as_float(s1);
    s2 = __float_as_uint(d1) & 0xFFFF0000u;
    float d2 = d1 - __uint_as_float(s2);
    s3 = __float_as_uint(d2) & 0xFFFF0000u;
}
__device__ __forceinline__ unsigned pack2(unsigned lo_hi16, unsigned hi_hi16) {
    return (lo_hi16 >> 16) | (hi_hi16 & 0xFFFF0000u);
}

// ---------------- init: build 16-ch cell state from 10-ch input ----------------
__global__ __launch_bounds__(256) void init_kernel(const float* __restrict__ inp,
                                                   float* __restrict__ cell) {
    int i = blockIdx.x * 256 + threadIdx.x;
    if (i >= NIMG * CH * HWSZ) return;
    int hw = i % HWSZ;
    int c  = (i / HWSZ) % CH;
    int n  = i / (CH * HWSZ);
    float v;
    if (c == 0)       v = 1.0f - inp[(n * 10 + 0) * HWSZ + hw];
    else if (c <= 10) v = inp[(n * 10 + (c - 1)) * HWSZ + hw];
    else              v = 0.0f;
    cell[i] = v;
}

// ---------------- prep: 3-way split weights into MFMA-friendly u16 arrays ------
// w1s: [3][48][64] (k padded 48..63 = 0), w2s: [3][16][64]
__global__ __launch_bounds__(256) void prep_weights(const float* __restrict__ w1,
                                                    const float* __restrict__ w2,
                                                    unsigned short* __restrict__ w1s,
                                                    unsigned short* __restrict__ w2s) {
    int i = blockIdx.x * 256 + threadIdx.x;     // 64 rows x 64 k
    if (i >= 64 * 64) return;
    int row = i >> 6, k = i & 63;
    float x = 0.0f;
    if (k < 48) x = (row < 48) ? w1[row * 48 + k] : w2[(row - 48) * 48 + k];
    unsigned s1, s2, s3;
    split3(x, s1, s2, s3);
    if (row < 48) {
        w1s[0 * 3072 + row * 64 + k] = (unsigned short)(s1 >> 16);
        w1s[1 * 3072 + row * 64 + k] = (unsigned short)(s2 >> 16);
        w1s[2 * 3072 + row * 64 + k] = (unsigned short)(s3 >> 16);
    } else {
        int r = row - 48;
        w2s[0 * 1024 + r * 64 + k] = (unsigned short)(s1 >> 16);
        w2s[1 * 1024 + r * 64 + k] = (unsigned short)(s2 >> 16);
        w2s[2 * 1024 + r * 64 + k] = (unsigned short)(s3 >> 16);
    }
}

// perception: p[0..15]=center, p[16..31]=sobel-x, p[32..47]=sobel-y
__device__ __forceinline__ void perception_at(const float* cs, int base, float* p) {
#pragma unroll
    for (int c = 0; c < CH; ++c) {
        const float* cc = cs + c * LA;
        float c00 = cc[base - LW - 1], c01 = cc[base - LW], c02 = cc[base - LW + 1];
        float c10 = cc[base - 1],      c11 = cc[base],      c12 = cc[base + 1];
        float c20 = cc[base + LW - 1], c21 = cc[base + LW], c22 = cc[base + LW + 1];
        p[c]      = c11;
        p[16 + c] = (c02 - c00 + 2.0f * (c12 - c10) + c22 - c20) * 0.125f;
        p[32 + c] = (c20 - c00 + 2.0f * (c21 - c01) + c22 - c02) * 0.125f;
    }
}

// ---------------- one fused CA step (MFMA matmuls) ----------------
__global__ __launch_bounds__(256, 3) void step_kernel(
    const float* __restrict__ cin, float* __restrict__ cout,
    const uint8_t* __restrict__ pre_in, uint8_t* __restrict__ pre_out,
    const unsigned short* __restrict__ w1s, const unsigned short* __restrict__ w2s,
    int gate) {

    __shared__ __align__(16) float cs[CH * LA];        // 25600 B
    __shared__ __align__(16) unsigned int ph[4 * 3 * 16 * 36];  // 27648 B; gm aliases
    float* gm = (float*)ph;   // used only in phases B/C (before phase E)

    const int tid = threadIdx.x;
    const int tx = tid & 15, ty = tid >> 4;
    const int bx = blockIdx.x * TILE, by = blockIdx.y * TILE;
    const int n = blockIdx.z;
    const float* cbase = cin + (size_t)n * CH * HWSZ;
    const uint8_t* pbase = pre_in + (size_t)n * HWSZ;

    // ---- hoisted coords: full 20x20 positions (ch0), two per thread ----
    const int lyA = tid / 20, lxA = tid % 20;
    const int gyA = by + lyA - 2, gxA = bx + lxA - 2;
    const bool okA = ((unsigned)gyA < HH) && ((unsigned)gxA < WW);
    const int offA = gyA * WW + gxA;

    const int rB = tid + 256;                  // valid when tid < 144
    const int lyB = rB / 20, lxB = rB % 20;
    const int gyB = by + lyB - 2, gxB = bx + lxB - 2;
    const bool okB = ((unsigned)gyB < HH) && ((unsigned)gxB < WW);
    const int offB = gyB * WW + gxB;

    // ---- hoisted coords: 18x18 region positions, two per thread ----
    const int j0 = tid;
    const int jy0 = j0 / 18, jx0 = j0 % 18;
    const int gy0 = by + jy0 - 1, gx0 = bx + jx0 - 1;
    const bool ok0 = ((unsigned)gy0 < HH) && ((unsigned)gx0 < WW);
    const int goff0 = gy0 * WW + gx0;
    const int lpos0 = (jy0 + 1) * LW + (jx0 + 1);

    const int j1 = tid + 256;                  // valid when tid < 68
    const int jy1 = j1 / 18, jx1 = j1 % 18;
    const int gy1 = by + jy1 - 1, gx1 = bx + jx1 - 1;
    const bool ok1 = ((unsigned)gy1 < HH) && ((unsigned)gx1 < WW);
    const int goff1 = gy1 * WW + gx1;
    const int lpos1 = (jy1 + 1) * LW + (jx1 + 1);

    // ---- A: stage raw ch0 (full 20x20, zero-fill OOB) ----
    cs[tid] = okA ? cbase[offA] : 0.0f;
    if (tid < 144) cs[rB] = okB ? cbase[offB] : 0.0f;
    __syncthreads();

    // ---- B: gate mask gm over 18x18 ----
    {
        float pm = -1e30f;
#pragma unroll
        for (int dy = -1; dy <= 1; ++dy)
#pragma unroll
            for (int dx = -1; dx <= 1; ++dx)
                pm = fmaxf(pm, cs[lpos0 + dy * LW + dx]);
        float mval = 1.0f;
        if (gate) {
            int pv = ok0 ? pbase[goff0] : 0;
            mval = (pv && pm > THR) ? 1.0f : 0.0f;
        }
        gm[j0] = mval;
    }
    if (tid < 68) {
        float pm = -1e30f;
#pragma unroll
        for (int dy = -1; dy <= 1; ++dy)
#pragma unroll
            for (int dx = -1; dx <= 1; ++dx)
                pm = fmaxf(pm, cs[lpos1 + dy * LW + dx]);
        float mval = 1.0f;
        if (gate) {
            int pv = ok1 ? pbase[goff1] : 0;
            mval = (pv && pm > THR) ? 1.0f : 0.0f;
        }
        gm[j1] = mval;
    }
    __syncthreads();

    // ---- C: gate ch0 in LDS; stage ch1..15 (18x18) with gate folded in ----
    {
        const float g = gm[j0];
        cs[lpos0] *= g;
        const float* gp = cbase + goff0;
#pragma unroll
        for (int c = 1; c < CH; ++c)
            cs[c * LA + lpos0] = (ok0 ? gp[c * HWSZ] : 0.0f) * g;
    }
    if (tid < 68) {
        const float g = gm[j1];
        cs[lpos1] *= g;
        const float* gp = cbase + goff1;
#pragma unroll
        for (int c = 1; c < CH; ++c)
            cs[c * LA + lpos1] = (ok1 ? gp[c * HWSZ] : 0.0f) * g;
    }
    __syncthreads();
    // (gm is dead from here; ph may be overwritten in phase E)

    // ---- D: pre(i) bits + perception + 3-way split/pack ----
    const int base = (ty + 2) * LW + (tx + 2);
    float pm = -1e30f;
#pragma unroll
    for (int dy = -1; dy <= 1; ++dy)
#pragma unroll
        for (int dx = -1; dx <= 1; ++dx)
            pm = fmaxf(pm, cs[base + dy * LW + dx]);
    pre_out[(size_t)n * HWSZ + (size_t)(by + ty) * WW + (bx + tx)] = (pm > THR) ? 1 : 0;

    float p[48];
    perception_at(cs, base, p);

    // pw* must stay in VGPRs: only constant indexing, NO pointer selects
    // (R6: dynamic `pws` select forced these to scratch -> 121us latency-bound).
    unsigned pw0[24], pw1[24], pw2[24];
#pragma unroll
    for (int w = 0; w < 24; ++w) {
        unsigned a1, a2, a3, b1, b2, b3;
        split3(p[2 * w],     a1, a2, a3);
        split3(p[2 * w + 1], b1, b2, b3);
        pw0[w] = pack2(a1, b1);
        pw1[w] = pack2(a2, b2);
        pw2[w] = pack2(a3, b3);
    }

    // ---- E: MFMA tile loop ----
    const int lane = tid & 63;
    const int px = lane & 15;       // B-frag col / D column
    const int q  = lane >> 4;       // quad
    const int wv = tid >> 6;        // wave in block
    unsigned int* phw = ph + wv * 1728;   // [3 splits][16 rows][36 words]

    frag a1h[3][2];                 // held w1 split-1 A-frags
#pragma unroll
    for (int ot = 0; ot < 3; ++ot)
#pragma unroll
        for (int kc = 0; kc < 2; ++kc)
            a1h[ot][kc] = *(const frag*)(w1s + (ot * 16 + px) * 64 + kc * 32 + q * 8);

    float* obase = cout + (size_t)n * CH * HWSZ;

#pragma unroll 1
    for (int t = 0; t < 4; ++t) {
        // quad t publishes its row's packed perception splits (+ zero k-pad).
        // Explicit per-split blocks, constant indices only.
        if (q == t) {
            unsigned int* r0 = phw + 0 * 576 + px * 36;
            unsigned int* r1 = phw + 1 * 576 + px * 36;
            unsigned int* r2 = phw + 2 * 576 + px * 36;
#pragma unroll
            for (int i = 0; i < 6; ++i) {
                u32x4 v0 = { pw0[4 * i], pw0[4 * i + 1], pw0[4 * i + 2], pw0[4 * i + 3] };
                *(u32x4*)(r0 + 4 * i) = v0;
            }
#pragma unroll
            for (int i = 0; i < 6; ++i) {
                u32x4 v1 = { pw1[4 * i], pw1[4 * i + 1], pw1[4 * i + 2], pw1[4 * i + 3] };
                *(u32x4*)(r1 + 4 * i) = v1;
            }
#pragma unroll
            for (int i = 0; i < 6; ++i) {
                u32x4 v2 = { pw2[4 * i], pw2[4 * i + 1], pw2[4 * i + 2], pw2[4 * i + 3] };
                *(u32x4*)(r2 + 4 * i) = v2;
            }
            u32x4 z = { 0, 0, 0, 0 };
            *(u32x4*)(r0 + 24) = z; *(u32x4*)(r0 + 28) = z;
            *(u32x4*)(r1 + 24) = z; *(u32x4*)(r1 + 28) = z;
            *(u32x4*)(r2 + 24) = z; *(u32x4*)(r2 + 28) = z;
        }
        MEMFENCE;   // publish must precede B-frag loads (same-wave LDS is in-order in HW)

        // layer 1: H[48 x 16px] = W1 * P
        f32x4 c1[3] = { {0,0,0,0}, {0,0,0,0}, {0,0,0,0} };
#pragma unroll
        for (int kc = 0; kc < 2; ++kc) {
            frag b1 = ldsfrag(phw + 0 * 576 + px * 36 + kc * 16 + q * 4);
            frag b2 = ldsfrag(phw + 1 * 576 + px * 36 + kc * 16 + q * 4);
            frag b3 = ldsfrag(phw + 2 * 576 + px * 36 + kc * 16 + q * 4);
#pragma unroll
            for (int ot = 0; ot < 3; ++ot) {
                frag a2 = *(const frag*)(w1s + 3072 + (ot * 16 + px) * 64 + kc * 32 + q * 8);
                frag a3 = *(const frag*)(w1s + 6144 + (ot * 16 + px) * 64 + kc * 32 + q * 8);
                c1[ot] = MFMA16(a1h[ot][kc], b1, c1[ot]);
                c1[ot] = MFMA16(a1h[ot][kc], b2, c1[ot]);
                c1[ot] = MFMA16(a2,          b1, c1[ot]);
                c1[ot] = MFMA16(a1h[ot][kc], b3, c1[ot]);
                c1[ot] = MFMA16(a2,          b2, c1[ot]);
                c1[ot] = MFMA16(a3,          b1, c1[ot]);
            }
        }
        MEMFENCE;   // B-frag loads of P must complete before H overwrite below

        // relu + split + write H into same buffer (words 0..23; zeros 24..31 persist)
#pragma unroll
        for (int ot = 0; ot < 3; ++ot) {
            unsigned s1b[4], s2b[4], s3b[4];
#pragma unroll
            for (int r = 0; r < 4; ++r) {
                float h = fmaxf(c1[ot][r], 0.0f);
                split3(h, s1b[r], s2b[r], s3b[r]);
            }
            u32x2 v0 = { pack2(s1b[0], s1b[1]), pack2(s1b[2], s1b[3]) };
            *(u32x2*)(phw + 0 * 576 + px * 36 + ot * 8 + q * 2) = v0;
            u32x2 v1 = { pack2(s2b[0], s2b[1]), pack2(s2b[2], s2b[3]) };
            *(u32x2*)(phw + 1 * 576 + px * 36 + ot * 8 + q * 2) = v1;
            u32x2 v2 = { pack2(s3b[0], s3b[1]), pack2(s3b[2], s3b[3]) };
            *(u32x2*)(phw + 2 * 576 + px * 36 + ot * 8 + q * 2) = v2;
        }
        MEMFENCE;   // H stores must precede layer-2 B-frag loads (R5 bug)

        // layer 2: cur[16ch x 16px] = W2 * relu(H) + cell   (C-init = residual)
        const int rloc = 4 * wv + t;
        f32x4 c2;
#pragma unroll
        for (int r = 0; r < 4; ++r)
            c2[r] = cs[(q * 4 + r) * LA + (rloc + 2) * LW + (px + 2)];
#pragma unroll
        for (int kc = 0; kc < 2; ++kc) {
            frag b1 = ldsfrag(phw + 0 * 576 + px * 36 + kc * 16 + q * 4);
            frag b2 = ldsfrag(phw + 1 * 576 + px * 36 + kc * 16 + q * 4);
            frag b3 = ldsfrag(phw + 2 * 576 + px * 36 + kc * 16 + q * 4);
            frag wa1 = *(const frag*)(w2s +    0 + px * 64 + kc * 32 + q * 8);
            frag wa2 = *(const frag*)(w2s + 1024 + px * 64 + kc * 32 + q * 8);
            frag wa3 = *(const frag*)(w2s + 2048 + px * 64 + kc * 32 + q * 8);
            c2 = MFMA16(wa1, b1, c2);
            c2 = MFMA16(wa1, b2, c2);
            c2 = MFMA16(wa2, b1, c2);
            c2 = MFMA16(wa1, b3, c2);
            c2 = MFMA16(wa2, b2, c2);
            c2 = MFMA16(wa3, b1, c2);
        }
        MEMFENCE;   // layer-2 B loads must precede next iteration's publish (WAR)

        // store ungated cur: lanes cover 16 px contiguous per channel row
        float* ob = obase + (size_t)(by + rloc) * WW + bx + px;
#pragma unroll
        for (int r = 0; r < 4; ++r)
            ob[(size_t)(q * 4 + r) * HWSZ] = c2[r];
    }
}

// ---------------- final: apply gate(30), emit channels 1..10 ----------------
__global__ __launch_bounds__(256) void final_kernel(
    const float* __restrict__ cur, const uint8_t* __restrict__ pre,
    float* __restrict__ out) {
    int i = blockIdx.x * 256 + threadIdx.x;
    if (i >= NIMG * HWSZ) return;
    int x = i % WW, y = (i / WW) % HH, n = i / HWSZ;
    const float* c0 = cur + (size_t)n * CH * HWSZ;
    float pm = -1e30f;
    for (int dy = -1; dy <= 1; ++dy) {
        int yy = y + dy;
        if ((unsigned)yy >= HH) continue;
        for (int dx = -1; dx <= 1; ++dx) {
            int xx = x + dx;
            if ((unsigned)xx >= WW) continue;
            pm = fmaxf(pm, c0[yy * WW + xx]);
        }
    }
    const bool alive = pre[i] && (pm > THR);
    float* ob = out + (size_t)n * 10 * HWSZ + y * WW + x;
#pragma unroll
    for (int k = 1; k <= 10; ++k)
        ob[(k - 1) * HWSZ] = alive ? c0[k * HWSZ + y * WW + x] : 0.0f;
}

extern "C" void kernel_launch(void* const* d_in, const int* in_sizes, int n_in,
                              void* d_out, int out_size, void* d_ws, size_t ws_size,
                              hipStream_t stream) {
    const float* inp = (const float*)d_in[0];
    const float* w1  = (const float*)d_in[1];
    const float* w2  = (const float*)d_in[2];
    float* out = (float*)d_out;

    const size_t SE = (size_t)NIMG * CH * HWSZ;    // 8,388,608 floats
    float* bufA = (float*)d_ws;
    float* bufB = bufA + SE;
    uint8_t* bitsA = (uint8_t*)(bufB + SE);
    uint8_t* bitsB = bitsA + (size_t)NIMG * HWSZ;
    unsigned short* w1s = (unsigned short*)(bitsB + (size_t)NIMG * HWSZ); // [3][48][64]
    unsigned short* w2s = w1s + 3 * 48 * 64;                              // [3][16][64]

    init_kernel<<<((int)SE + 255) / 256, 256, 0, stream>>>(inp, bufA);
    prep_weights<<<16, 256, 0, stream>>>(w1, w2, w1s, w2s);

    dim3 grid(WW / TILE, HH / TILE, NIMG);
    float* src = bufA;
    float* dst = bufB;
    uint8_t* pin = bitsB;   // unused on first iter (gate=0)
    uint8_t* pout = bitsA;
    for (int it = 0; it < NUM_ITER; ++it) {
        step_kernel<<<grid, 256, 0, stream>>>(src, dst, pin, pout, w1s, w2s,
                                              it == 0 ? 0 : 1);
        float* t = src; src = dst; dst = t;
        uint8_t* tb = pin; pin = pout; pout = tb;
    }
    // after loop: src = cur(30), pin = pre(30) bits
    final_kernel<<<(NIMG * HWSZ + 255) / 256, 256, 0, stream>>>(src, pin, out);
}

// Round 8
// 3413.066 us; speedup vs baseline: 1.0267x; 1.0026x over previous
//
#include <hip/hip_runtime.h>
#include <stdint.h>

#define HH 128
#define WW 128
#define NIMG 32
#define CH 16
#define TILE 16
#define LW 20            // 16 + 2*2 halo
#define LA (LW * LW)     // 400 floats per channel plane
#define NUM_ITER 30
#define THR 0.1f
#define HWSZ (HH * WW)

typedef __attribute__((ext_vector_type(8))) short frag;      // 8 bf16 = A/B operand
typedef __attribute__((ext_vector_type(4))) float f32x4;     // C/D
typedef __attribute__((ext_vector_type(4))) unsigned int u32x4;
typedef __attribute__((ext_vector_type(2))) unsigned int u32x2;
#define MFMA16(a, b, c) __builtin_amdgcn_mfma_f32_16x16x32_bf16(a, b, c, 0, 0, 0)
// Compiler memory fence: stops TBAA-based reordering of LDS uint-stores vs
// frag-loads (same-wave LDS is in-order in HW; this only constrains the compiler).
#define MEMFENCE asm volatile("" ::: "memory")

// Load an MFMA frag from LDS through uint typing (aliases with uint stores).
__device__ __forceinline__ frag ldsfrag(const unsigned int* p) {
    u32x4 v = *(const u32x4*)p;
    return __builtin_bit_cast(frag, v);
}

// 3-way bf16 split: x ~= s1 + s2 + s3, dropped residual <= ~2^-23|x|.
// Level 1 RNE (carry trick), levels 2/3 truncate. Outputs hold bf16 bits in TOP 16.
__device__ __forceinline__ void split3(float x, unsigned& s1, unsigned& s2, unsigned& s3) {
    unsigned u = __float_as_uint(x);
    unsigned r = u + 0x7FFF + ((u >> 16) & 1);
    s1 = r & 0xFFFF0000u;
    float d1 = x - __uint_as_float(s1);
    s2 = __float_as_uint(d1) & 0xFFFF0000u;
    float d2 = d1 - __uint_as_float(s2);
    s3 = __float_as_uint(d2) & 0xFFFF0000u;
}
__device__ __forceinline__ unsigned pack2(unsigned lo_hi16, unsigned hi_hi16) {
    return (lo_hi16 >> 16) | (hi_hi16 & 0xFFFF0000u);
}

// ---------------- init: build 16-ch cell state from 10-ch input ----------------
__global__ __launch_bounds__(256) void init_kernel(const float* __restrict__ inp,
                                                   float* __restrict__ cell) {
    int i = blockIdx.x * 256 + threadIdx.x;
    if (i >= NIMG * CH * HWSZ) return;
    int hw = i % HWSZ;
    int c  = (i / HWSZ) % CH;
    int n  = i / (CH * HWSZ);
    float v;
    if (c == 0)       v = 1.0f - inp[(n * 10 + 0) * HWSZ + hw];
    else if (c <= 10) v = inp[(n * 10 + (c - 1)) * HWSZ + hw];
    else              v = 0.0f;
    cell[i] = v;
}

// ---------------- prep: 3-way split weights into MFMA-friendly u16 arrays ------
// w1s: [3][48][64] (k padded 48..63 = 0), w2s: [3][16][64]
__global__ __launch_bounds__(256) void prep_weights(const float* __restrict__ w1,
                                                    const float* __restrict__ w2,
                                                    unsigned short* __restrict__ w1s,
                                                    unsigned short* __restrict__ w2s) {
    int i = blockIdx.x * 256 + threadIdx.x;     // 64 rows x 64 k
    if (i >= 64 * 64) return;
    int row = i >> 6, k = i & 63;
    float x = 0.0f;
    if (k < 48) x = (row < 48) ? w1[row * 48 + k] : w2[(row - 48) * 48 + k];
    unsigned s1, s2, s3;
    split3(x, s1, s2, s3);
    if (row < 48) {
        w1s[0 * 3072 + row * 64 + k] = (unsigned short)(s1 >> 16);
        w1s[1 * 3072 + row * 64 + k] = (unsigned short)(s2 >> 16);
        w1s[2 * 3072 + row * 64 + k] = (unsigned short)(s3 >> 16);
    } else {
        int r = row - 48;
        w2s[0 * 1024 + r * 64 + k] = (unsigned short)(s1 >> 16);
        w2s[1 * 1024 + r * 64 + k] = (unsigned short)(s2 >> 16);
        w2s[2 * 1024 + r * 64 + k] = (unsigned short)(s3 >> 16);
    }
}

// ---- phase-E macros: all temporaries are named scalars (NO private arrays —
// R6/R7's long-lived p[48]/pw[72] arrays went to scratch: +8MB/step writes). ----

// perception for one channel (cc0+j) of pixel at cs-index pc
#define PERC(j, C, X, Y) { \
    const float* cp_ = cs + (cc0 + (j)) * LA + pc; \
    float a_ = cp_[-LW-1], b_ = cp_[-LW], c_ = cp_[-LW+1]; \
    float d_ = cp_[-1],    e_ = cp_[0],  f_ = cp_[1]; \
    float g_ = cp_[LW-1],  h_ = cp_[LW], i_ = cp_[LW+1]; \
    C = e_; \
    X = (c_ - a_ + 2.0f * (f_ - d_) + i_ - g_) * 0.125f; \
    Y = (g_ - a_ + 2.0f * (h_ - b_) + i_ - c_) * 0.125f; }

// publish 4 values (k = 2*(woff+2q) .. +3) as 3-way splits into the wave's
// B-operand buffer: word (woff + 2q) of each split plane, row px. Layout
// verified end-to-end in R6/R7 (absmax == fp32 version's).
#define PUB(woff, v0, v1, v2, v3) { \
    unsigned x1_,x2_,x3_, y1_,y2_,y3_, z1_,z2_,z3_, u1_,u2_,u3_; \
    split3(v0, x1_, x2_, x3_); split3(v1, y1_, y2_, y3_); \
    split3(v2, z1_, z2_, z3_); split3(v3, u1_, u2_, u3_); \
    u32x2 wv_; \
    wv_.x = pack2(x1_, y1_); wv_.y = pack2(z1_, u1_); \
    *(u32x2*)(phw + 0 * 576 + px * 36 + (woff) + 2 * q) = wv_; \
    wv_.x = pack2(x2_, y2_); wv_.y = pack2(z2_, u2_); \
    *(u32x2*)(phw + 1 * 576 + px * 36 + (woff) + 2 * q) = wv_; \
    wv_.x = pack2(x3_, y3_); wv_.y = pack2(z3_, u3_); \
    *(u32x2*)(phw + 2 * 576 + px * 36 + (woff) + 2 * q) = wv_; }

// layer-1: 6 products of (w1 split_i, P split_j), i+j<=4, per kc chunk.
// Two independent accumulator chains (kc0->acc0, kc1->acc1).
#define L1OT(ot, A0, A1, acc0, acc1) { \
    frag a20_ = *(const frag*)(w1s + 3072 + ((ot) * 16 + px) * 64 +  0 + q * 8); \
    frag a30_ = *(const frag*)(w1s + 6144 + ((ot) * 16 + px) * 64 +  0 + q * 8); \
    frag a21_ = *(const frag*)(w1s + 3072 + ((ot) * 16 + px) * 64 + 32 + q * 8); \
    frag a31_ = *(const frag*)(w1s + 6144 + ((ot) * 16 + px) * 64 + 32 + q * 8); \
    acc0 = MFMA16(A0,   b10, acc0); acc0 = MFMA16(A0,   b20, acc0); \
    acc0 = MFMA16(a20_, b10, acc0); acc0 = MFMA16(A0,   b30, acc0); \
    acc0 = MFMA16(a20_, b20, acc0); acc0 = MFMA16(a30_, b10, acc0); \
    acc1 = MFMA16(A1,   b11, acc1); acc1 = MFMA16(A1,   b21, acc1); \
    acc1 = MFMA16(a21_, b11, acc1); acc1 = MFMA16(A1,   b31, acc1); \
    acc1 = MFMA16(a21_, b21, acc1); acc1 = MFMA16(a31_, b11, acc1); }

// relu(H) from two chains, split, write back into B-buffer (words ot*8+2q)
#define HWB(ot, acc0, acc1) { \
    float h0_ = fmaxf(acc0.x + acc1.x, 0.0f); \
    float h1_ = fmaxf(acc0.y + acc1.y, 0.0f); \
    float h2_ = fmaxf(acc0.z + acc1.z, 0.0f); \
    float h3_ = fmaxf(acc0.w + acc1.w, 0.0f); \
    PUB((ot) * 8, h0_, h1_, h2_, h3_); }

// ---------------- one fused CA step (MFMA matmuls) ----------------
__global__ __launch_bounds__(256, 3) void step_kernel(
    const float* __restrict__ cin, float* __restrict__ cout,
    const uint8_t* __restrict__ pre_in, uint8_t* __restrict__ pre_out,
    const unsigned short* __restrict__ w1s, const unsigned short* __restrict__ w2s,
    int gate) {

    __shared__ __align__(16) float cs[CH * LA];        // 25600 B
    __shared__ __align__(16) unsigned int ph[4 * 3 * 16 * 36];  // 27648 B; gm aliases
    float* gm = (float*)ph;   // used only in phases B/C (dead before phase E writes)

    const int tid = threadIdx.x;
    const int tx = tid & 15, ty = tid >> 4;
    const int bx = blockIdx.x * TILE, by = blockIdx.y * TILE;
    const int n = blockIdx.z;
    const float* cbase = cin + (size_t)n * CH * HWSZ;
    const uint8_t* pbase = pre_in + (size_t)n * HWSZ;

    // ---- hoisted coords: full 20x20 positions (ch0), two per thread ----
    const int lyA = tid / 20, lxA = tid % 20;
    const int gyA = by + lyA - 2, gxA = bx + lxA - 2;
    const bool okA = ((unsigned)gyA < HH) && ((unsigned)gxA < WW);
    const int offA = gyA * WW + gxA;

    const int rB = tid + 256;                  // valid when tid < 144
    const int lyB = rB / 20, lxB = rB % 20;
    const int gyB = by + lyB - 2, gxB = bx + lxB - 2;
    const bool okB = ((unsigned)gyB < HH) && ((unsigned)gxB < WW);
    const int offB = gyB * WW + gxB;

    // ---- hoisted coords: 18x18 region positions, two per thread ----
    const int j0 = tid;
    const int jy0 = j0 / 18, jx0 = j0 % 18;
    const int gy0 = by + jy0 - 1, gx0 = bx + jx0 - 1;
    const bool ok0 = ((unsigned)gy0 < HH) && ((unsigned)gx0 < WW);
    const int goff0 = gy0 * WW + gx0;
    const int lpos0 = (jy0 + 1) * LW + (jx0 + 1);

    const int j1 = tid + 256;                  // valid when tid < 68
    const int jy1 = j1 / 18, jx1 = j1 % 18;
    const int gy1 = by + jy1 - 1, gx1 = bx + jx1 - 1;
    const bool ok1 = ((unsigned)gy1 < HH) && ((unsigned)gx1 < WW);
    const int goff1 = gy1 * WW + gx1;
    const int lpos1 = (jy1 + 1) * LW + (jx1 + 1);

    // ---- A: stage raw ch0 (full 20x20, zero-fill OOB) ----
    cs[tid] = okA ? cbase[offA] : 0.0f;
    if (tid < 144) cs[rB] = okB ? cbase[offB] : 0.0f;
    __syncthreads();

    // ---- B: gate mask gm over 18x18 ----
    {
        float pm = -1e30f;
#pragma unroll
        for (int dy = -1; dy <= 1; ++dy)
#pragma unroll
            for (int dx = -1; dx <= 1; ++dx)
                pm = fmaxf(pm, cs[lpos0 + dy * LW + dx]);
        float mval = 1.0f;
        if (gate) {
            int pv = ok0 ? pbase[goff0] : 0;
            mval = (pv && pm > THR) ? 1.0f : 0.0f;
        }
        gm[j0] = mval;
    }
    if (tid < 68) {
        float pm = -1e30f;
#pragma unroll
        for (int dy = -1; dy <= 1; ++dy)
#pragma unroll
            for (int dx = -1; dx <= 1; ++dx)
                pm = fmaxf(pm, cs[lpos1 + dy * LW + dx]);
        float mval = 1.0f;
        if (gate) {
            int pv = ok1 ? pbase[goff1] : 0;
            mval = (pv && pm > THR) ? 1.0f : 0.0f;
        }
        gm[j1] = mval;
    }
    __syncthreads();

    // ---- C: gate ch0 in LDS; stage ch1..15 (18x18) with gate folded in ----
    {
        const float g = gm[j0];
        cs[lpos0] *= g;
        const float* gp = cbase + goff0;
#pragma unroll
        for (int c = 1; c < CH; ++c)
            cs[c * LA + lpos0] = (ok0 ? gp[c * HWSZ] : 0.0f) * g;
    }
    if (tid < 68) {
        const float g = gm[j1];
        cs[lpos1] *= g;
        const float* gp = cbase + goff1;
#pragma unroll
        for (int c = 1; c < CH; ++c)
            cs[c * LA + lpos1] = (ok1 ? gp[c * HWSZ] : 0.0f) * g;
    }
    __syncthreads();
    // (gm is dead from here; ph is overwritten in phase E)

    // ---- D: pre(i) bits only ----
    {
        const int dbase = (ty + 2) * LW + (tx + 2);
        float pm = -1e30f;
#pragma unroll
        for (int dy = -1; dy <= 1; ++dy)
#pragma unroll
            for (int dx = -1; dx <= 1; ++dx)
                pm = fmaxf(pm, cs[dbase + dy * LW + dx]);
        pre_out[(size_t)n * HWSZ + (size_t)(by + ty) * WW + (bx + tx)] = (pm > THR) ? 1 : 0;
    }

    // ---- E: MFMA tile loop, fully tile-local (no cross-tile private state
    // except 6 held w1 frags) ----
    const int lane = tid & 63;
    const int px = lane & 15;       // B-row / D-column (pixel within tile row)
    const int q  = lane >> 4;       // quad: channel group for perception, k-subchunk for frags
    const int wv = tid >> 6;        // wave in block
    unsigned int* phw = ph + wv * 1728;   // [3 splits][16 rows][36 words]

    // zero the k-pad words 24..31 (k=48..63) once; data stores never touch them
    {
        u32x4 z = { 0, 0, 0, 0 };
        int s0 = lane >> 5, rem = lane & 31;
        *(u32x4*)(phw + s0 * 576 + (rem >> 1) * 36 + 24 + 4 * (rem & 1)) = z;
        if (lane < 32)
            *(u32x4*)(phw + 2 * 576 + (lane >> 1) * 36 + 24 + 4 * (lane & 1)) = z;
    }

    // held w1 split-1 A-frags (6 frags = 24 VGPRs; L1-resident reloads for a2/a3)
    frag a1h00 = *(const frag*)(w1s + (0 * 16 + px) * 64 +  0 + q * 8);
    frag a1h01 = *(const frag*)(w1s + (0 * 16 + px) * 64 + 32 + q * 8);
    frag a1h10 = *(const frag*)(w1s + (1 * 16 + px) * 64 +  0 + q * 8);
    frag a1h11 = *(const frag*)(w1s + (1 * 16 + px) * 64 + 32 + q * 8);
    frag a1h20 = *(const frag*)(w1s + (2 * 16 + px) * 64 +  0 + q * 8);
    frag a1h21 = *(const frag*)(w1s + (2 * 16 + px) * 64 + 32 + q * 8);

    float* obase = cout + (size_t)n * CH * HWSZ;

#pragma unroll 1
    for (int t = 0; t < 4; ++t) {
        const int rloc = 4 * wv + t;              // pixel row this wave computes
        const int cc0 = 4 * q;                    // this lane's channel group
        const int pc = (rloc + 2) * LW + (px + 2);

        // distributed perception: 64 lanes cover 16 px x 4 channel-groups
        float vc0, vx0, vy0, vc1, vx1, vy1, vc2, vx2, vy2, vc3, vx3, vy3;
        PERC(0, vc0, vx0, vy0);
        PERC(1, vc1, vx1, vy1);
        PERC(2, vc2, vx2, vy2);
        PERC(3, vc3, vx3, vy3);
        PUB(0,  vc0, vc1, vc2, vc3);    // center  -> k 0..15  (words 0..7)
        PUB(8,  vx0, vx1, vx2, vx3);    // sobel-x -> k 16..31 (words 8..15)
        PUB(16, vy0, vy1, vy2, vy3);    // sobel-y -> k 32..47 (words 16..23)
        MEMFENCE;   // publish must precede B-frag loads

        // layer 1: H[48 x 16px] = W1 * P   (6 independent accumulator chains)
        frag b10 = ldsfrag(phw + 0 * 576 + px * 36 +  0 + q * 4);
        frag b20 = ldsfrag(phw + 1 * 576 + px * 36 +  0 + q * 4);
        frag b30 = ldsfrag(phw + 2 * 576 + px * 36 +  0 + q * 4);
        frag b11 = ldsfrag(phw + 0 * 576 + px * 36 + 16 + q * 4);
        frag b21 = ldsfrag(phw + 1 * 576 + px * 36 + 16 + q * 4);
        frag b31 = ldsfrag(phw + 2 * 576 + px * 36 + 16 + q * 4);
        f32x4 zz = { 0, 0, 0, 0 };
        f32x4 c1a0 = zz, c1b0 = zz, c1a1 = zz, c1b1 = zz, c1a2 = zz, c1b2 = zz;
        L1OT(0, a1h00, a1h01, c1a0, c1b0);
        L1OT(1, a1h10, a1h11, c1a1, c1b1);
        L1OT(2, a1h20, a1h21, c1a2, c1b2);
        MEMFENCE;   // P-frag loads must complete before H overwrite

        HWB(0, c1a0, c1b0);
        HWB(1, c1a1, c1b1);
        HWB(2, c1a2, c1b2);
        MEMFENCE;   // H stores must precede layer-2 B-frag loads

        // layer 2: cur[16ch x 16px] = W2 * relu(H) + cell  (2 chains)
        frag h10 = ldsfrag(phw + 0 * 576 + px * 36 +  0 + q * 4);
        frag h20 = ldsfrag(phw + 1 * 576 + px * 36 +  0 + q * 4);
        frag h30 = ldsfrag(phw + 2 * 576 + px * 36 +  0 + q * 4);
        frag h11 = ldsfrag(phw + 0 * 576 + px * 36 + 16 + q * 4);
        frag h21 = ldsfrag(phw + 1 * 576 + px * 36 + 16 + q * 4);
        frag h31 = ldsfrag(phw + 2 * 576 + px * 36 + 16 + q * 4);
        frag wa10 = *(const frag*)(w2s +    0 + px * 64 +  0 + q * 8);
        frag wa20 = *(const frag*)(w2s + 1024 + px * 64 +  0 + q * 8);
        frag wa30 = *(const frag*)(w2s + 2048 + px * 64 +  0 + q * 8);
        frag wa11 = *(const frag*)(w2s +    0 + px * 64 + 32 + q * 8);
        frag wa21 = *(const frag*)(w2s + 1024 + px * 64 + 32 + q * 8);
        frag wa31 = *(const frag*)(w2s + 2048 + px * 64 + 32 + q * 8);
        f32x4 c2a, c2b = zz;
        c2a.x = cs[(q * 4 + 0) * LA + pc];   // residual = gated cell
        c2a.y = cs[(q * 4 + 1) * LA + pc];
        c2a.z = cs[(q * 4 + 2) * LA + pc];
        c2a.w = cs[(q * 4 + 3) * LA + pc];
        c2a = MFMA16(wa10, h10, c2a); c2a = MFMA16(wa10, h20, c2a);
        c2a = MFMA16(wa20, h10, c2a); c2a = MFMA16(wa10, h30, c2a);
        c2a = MFMA16(wa20, h20, c2a); c2a = MFMA16(wa30, h10, c2a);
        c2b = MFMA16(wa11, h11, c2b); c2b = MFMA16(wa11, h21, c2b);
        c2b = MFMA16(wa21, h11, c2b); c2b = MFMA16(wa11, h31, c2b);
        c2b = MFMA16(wa21, h21, c2b); c2b = MFMA16(wa31, h11, c2b);
        MEMFENCE;   // layer-2 H loads must precede next tile's publish (WAR)

        f32x4 c2 = c2a + c2b;
        float* ob = obase + (size_t)(by + rloc) * WW + bx + px;
        ob[(size_t)(q * 4 + 0) * HWSZ] = c2.x;
        ob[(size_t)(q * 4 + 1) * HWSZ] = c2.y;
        ob[(size_t)(q * 4 + 2) * HWSZ] = c2.z;
        ob[(size_t)(q * 4 + 3) * HWSZ] = c2.w;
    }
}

// ---------------- final: apply gate(30), emit channels 1..10 ----------------
__global__ __launch_bounds__(256) void final_kernel(
    const float* __restrict__ cur, const uint8_t* __restrict__ pre,
    float* __restrict__ out) {
    int i = blockIdx.x * 256 + threadIdx.x;
    if (i >= NIMG * HWSZ) return;
    int x = i % WW, y = (i / WW) % HH, n = i / HWSZ;
    const float* c0 = cur + (size_t)n * CH * HWSZ;
    float pm = -1e30f;
    for (int dy = -1; dy <= 1; ++dy) {
        int yy = y + dy;
        if ((unsigned)yy >= HH) continue;
        for (int dx = -1; dx <= 1; ++dx) {
            int xx = x + dx;
            if ((unsigned)xx >= WW) continue;
            pm = fmaxf(pm, c0[yy * WW + xx]);
        }
    }
    const bool alive = pre[i] && (pm > THR);
    float* ob = out + (size_t)n * 10 * HWSZ + y * WW + x;
#pragma unroll
    for (int k = 1; k <= 10; ++k)
        ob[(k - 1) * HWSZ] = alive ? c0[k * HWSZ + y * WW + x] : 0.0f;
}

extern "C" void kernel_launch(void* const* d_in, const int* in_sizes, int n_in,
                              void* d_out, int out_size, void* d_ws, size_t ws_size,
                              hipStream_t stream) {
    const float* inp = (const float*)d_in[0];
    const float* w1  = (const float*)d_in[1];
    const float* w2  = (const float*)d_in[2];
    float* out = (float*)d_out;

    const size_t SE = (size_t)NIMG * CH * HWSZ;    // 8,388,608 floats
    float* bufA = (float*)d_ws;
    float* bufB = bufA + SE;
    uint8_t* bitsA = (uint8_t*)(bufB + SE);
    uint8_t* bitsB = bitsA + (size_t)NIMG * HWSZ;
    unsigned short* w1s = (unsigned short*)(bitsB + (size_t)NIMG * HWSZ); // [3][48][64]
    unsigned short* w2s = w1s + 3 * 48 * 64;                              // [3][16][64]

    init_kernel<<<((int)SE + 255) / 256, 256, 0, stream>>>(inp, bufA);
    prep_weights<<<16, 256, 0, stream>>>(w1, w2, w1s, w2s);

    dim3 grid(WW / TILE, HH / TILE, NIMG);
    float* src = bufA;
    float* dst = bufB;
    uint8_t* pin = bitsB;   // unused on first iter (gate=0)
    uint8_t* pout = bitsA;
    for (int it = 0; it < NUM_ITER; ++it) {
        step_kernel<<<grid, 256, 0, stream>>>(src, dst, pin, pout, w1s, w2s,
                                              it == 0 ? 0 : 1);
        float* t = src; src = dst; dst = t;
        uint8_t* tb = pin; pin = pout; pout = tb;
    }
    // after loop: src = cur(30), pin = pre(30) bits
    final_kernel<<<(NIMG * HWSZ + 255) / 256, 256, 0, stream>>>(src, pin, out);
}

// Round 9
// 2971.433 us; speedup vs baseline: 1.1793x; 1.1486x over previous
//
#include <hip/hip_runtime.h>
#include <stdint.h>

#define HH 128
#define WW 128
#define NIMG 32
#define CH 16
#define TILE 16
#define LW 20            // raw-ch0 tile stride (20x20, halo 2)
#define NUM_ITER 30
#define THR 0.1f
#define HWSZ (HH * WW)
#define CPS 325          // gated-cell plane stride in floats (18x18 data; odd => bank spread)
#define PHROW 26         // B-buffer row stride in words (24 data + 2 pad; even => b64 align)
#define PHPLANE 416      // 16 rows * 26
#define PHWAVE 1248      // 3 split planes * 416

typedef __attribute__((ext_vector_type(8))) short frag;      // 8 bf16 = K32 A/B operand
typedef __attribute__((ext_vector_type(4))) float f32x4;     // C/D
typedef __attribute__((ext_vector_type(4))) unsigned int u32x4;
typedef __attribute__((ext_vector_type(2))) unsigned int u32x2;
#define MFMA16(a, b, c) __builtin_amdgcn_mfma_f32_16x16x32_bf16(a, b, c, 0, 0, 0)
// Compiler memory fence: stops TBAA-based reordering of LDS uint-stores vs
// frag-loads (same-wave LDS is in-order in HW; this only constrains the compiler).
#define MEMFENCE asm volatile("" ::: "memory")

// 3-way bf16 split: x ~= s1+s2+s3 (s1 RNE, s2/s3 trunc), residual <= ~2^-22|x|.
__device__ __forceinline__ void split3(float x, unsigned& s1, unsigned& s2, unsigned& s3) {
    unsigned u = __float_as_uint(x);
    unsigned r = u + 0x7FFF + ((u >> 16) & 1);
    s1 = r & 0xFFFF0000u;
    float d1 = x - __uint_as_float(s1);
    s2 = __float_as_uint(d1) & 0xFFFF0000u;
    float d2 = d1 - __uint_as_float(s2);
    s3 = __float_as_uint(d2) & 0xFFFF0000u;
}
__device__ __forceinline__ unsigned pack2(unsigned lo_hi16, unsigned hi_hi16) {
    return (lo_hi16 >> 16) | (hi_hi16 & 0xFFFF0000u);
}

// B-frag loads: two ds_read_b64 (conflict-free at stride 26; b128 would need 16B align)
__device__ __forceinline__ frag bfrag_kc0(const unsigned* base, int q) {
    const unsigned* p = base + 4 * q;
    u32x2 a = *(const u32x2*)p, b = *(const u32x2*)(p + 2);
    u32x4 v = { a.x, a.y, b.x, b.y };
    return __builtin_bit_cast(frag, v);
}
__device__ __forceinline__ frag bfrag_kc1(const unsigned* base, const unsigned* zbl, int q) {
    const unsigned* p = (q < 2) ? (base + 16 + 4 * q) : zbl;   // k=48..63 are shared zeros
    u32x2 a = *(const u32x2*)p, b = *(const u32x2*)(p + 2);
    u32x4 v = { a.x, a.y, b.x, b.y };
    return __builtin_bit_cast(frag, v);
}

// ---------------- init ----------------
__global__ __launch_bounds__(256) void init_kernel(const float* __restrict__ inp,
                                                   float* __restrict__ cell) {
    int i = blockIdx.x * 256 + threadIdx.x;
    if (i >= NIMG * CH * HWSZ) return;
    int hw = i % HWSZ;
    int c  = (i / HWSZ) % CH;
    int n  = i / (CH * HWSZ);
    float v;
    if (c == 0)       v = 1.0f - inp[(n * 10 + 0) * HWSZ + hw];
    else if (c <= 10) v = inp[(n * 10 + (c - 1)) * HWSZ + hw];
    else              v = 0.0f;
    cell[i] = v;
}

// ---------------- prep: 3-way split weights, K padded to 64 (A-side zeros) ----
__global__ __launch_bounds__(256) void prep_weights(const float* __restrict__ w1,
                                                    const float* __restrict__ w2,
                                                    unsigned short* __restrict__ w1s,
                                                    unsigned short* __restrict__ w2s) {
    int i = blockIdx.x * 256 + threadIdx.x;     // 64 rows x 64 k
    if (i >= 64 * 64) return;
    int row = i >> 6, k = i & 63;
    float x = 0.0f;
    if (k < 48) x = (row < 48) ? w1[row * 48 + k] : w2[(row - 48) * 48 + k];
    unsigned s1, s2, s3;
    split3(x, s1, s2, s3);
    if (row < 48) {
        w1s[0 * 3072 + row * 64 + k] = (unsigned short)(s1 >> 16);
        w1s[1 * 3072 + row * 64 + k] = (unsigned short)(s2 >> 16);
        w1s[2 * 3072 + row * 64 + k] = (unsigned short)(s3 >> 16);
    } else {
        int r = row - 48;
        w2s[0 * 1024 + r * 64 + k] = (unsigned short)(s1 >> 16);
        w2s[1 * 1024 + r * 64 + k] = (unsigned short)(s2 >> 16);
        w2s[2 * 1024 + r * 64 + k] = (unsigned short)(s3 >> 16);
    }
}

// perception for channel (cc0_+j) at gated-cell position ppos_ (stride-18 in CPS planes)
#define PERC(j, C, X, Y) { \
    const float* cp_ = cp + (cc0_ + (j)) * CPS + ppos_; \
    float a_ = cp_[-19], b_ = cp_[-18], c_ = cp_[-17]; \
    float d_ = cp_[-1],  e_ = cp_[0],  f_ = cp_[1]; \
    float g_ = cp_[17],  h_ = cp_[18], i_ = cp_[19]; \
    C = e_; \
    X = (c_ - a_ + 2.0f * (f_ - d_) + i_ - g_) * 0.125f; \
    Y = (g_ - a_ + 2.0f * (h_ - b_) + i_ - c_) * 0.125f; }

// split 4 values 3-way, pack into three u32x2 (named scalars only — no arrays)
#define SPLITPACK(v0, v1, v2, v3, O1, O2, O3) { \
    unsigned a1_,a2_,a3_, b1_,b2_,b3_, c1_,c2_,c3_, d1_,d2_,d3_; \
    split3(v0, a1_, a2_, a3_); split3(v1, b1_, b2_, b3_); \
    split3(v2, c1_, c2_, c3_); split3(v3, d1_, d2_, d3_); \
    O1.x = pack2(a1_, b1_); O1.y = pack2(c1_, d1_); \
    O2.x = pack2(a2_, b2_); O2.y = pack2(c2_, d2_); \
    O3.x = pack2(a3_, b3_); O3.y = pack2(c3_, d3_); }

// perception+split for row RN -> payload registers p1c..p3y
#define MAKEPAYLOAD(RN) { \
    const int ppos_ = ((RN) + 1) * 18 + px + 1; \
    const int cc0_ = 4 * q; \
    float vc0,vx0,vy0, vc1,vx1,vy1, vc2,vx2,vy2, vc3,vx3,vy3; \
    PERC(0, vc0, vx0, vy0); PERC(1, vc1, vx1, vy1); \
    PERC(2, vc2, vx2, vy2); PERC(3, vc3, vx3, vy3); \
    SPLITPACK(vc0, vc1, vc2, vc3, p1c, p2c, p3c); \
    SPLITPACK(vx0, vx1, vx2, vx3, p1x, p2x, p3x); \
    SPLITPACK(vy0, vy1, vy2, vy3, p1y, p2y, p3y); }

// layer-1: 6 split-products per kc chunk; 2 independent acc chains
#define L1OT(OT, A0, A1, acc0, acc1) { \
    frag a20_ = *(const frag*)(w1s + 3072 + ((OT) * 16 + px) * 64 +  0 + q * 8); \
    frag a30_ = *(const frag*)(w1s + 6144 + ((OT) * 16 + px) * 64 +  0 + q * 8); \
    frag a21_ = *(const frag*)(w1s + 3072 + ((OT) * 16 + px) * 64 + 32 + q * 8); \
    frag a31_ = *(const frag*)(w1s + 6144 + ((OT) * 16 + px) * 64 + 32 + q * 8); \
    acc0 = MFMA16(A0,   b10, acc0); acc0 = MFMA16(A0,   b20, acc0); \
    acc0 = MFMA16(a20_, b10, acc0); acc0 = MFMA16(A0,   b30, acc0); \
    acc0 = MFMA16(a20_, b20, acc0); acc0 = MFMA16(a30_, b10, acc0); \
    acc1 = MFMA16(A1,   b11, acc1); acc1 = MFMA16(A1,   b21, acc1); \
    acc1 = MFMA16(a21_, b11, acc1); acc1 = MFMA16(A1,   b31, acc1); \
    acc1 = MFMA16(a21_, b21, acc1); acc1 = MFMA16(a31_, b11, acc1); }

// relu(H) -> split -> write back into B-buffer at k = OT*16..OT*16+15
#define HWB(OT, acc0, acc1) { \
    float h0_ = fmaxf(acc0.x + acc1.x, 0.0f); \
    float h1_ = fmaxf(acc0.y + acc1.y, 0.0f); \
    float h2_ = fmaxf(acc0.z + acc1.z, 0.0f); \
    float h3_ = fmaxf(acc0.w + acc1.w, 0.0f); \
    u32x2 o1_, o2_, o3_; \
    SPLITPACK(h0_, h1_, h2_, h3_, o1_, o2_, o3_); \
    *(u32x2*)(phw + 0 * PHPLANE + pxw + (OT) * 8) = o1_; \
    *(u32x2*)(phw + 1 * PHPLANE + pxw + (OT) * 8) = o2_; \
    *(u32x2*)(phw + 2 * PHPLANE + pxw + (OT) * 8) = o3_; }

// ---------------- one fused CA step ----------------
// LDS 40800B -> 4 blocks/CU; VGPR cap 128 via launch_bounds(256,4) -> 16 waves/CU.
__global__ __launch_bounds__(256, 4) void step_kernel(
    const float* __restrict__ cin, float* __restrict__ cout,
    const uint8_t* __restrict__ pre_in, uint8_t* __restrict__ pre_out,
    const unsigned short* __restrict__ w1s, const unsigned short* __restrict__ w2s,
    int gate) {

    __shared__ __align__(16) float cp[CH * CPS + 8];   // gated cells (18x18/ch) + 8-word zero blk
    __shared__ __align__(16) unsigned int ph[4 * PHWAVE];  // per-wave B-buffers; gm+raw-ch0 alias
    float* gmf  = (float*)ph;          // [0,324): gate mask      (dead before phase E)
    float* cs20 = (float*)ph + 324;    // [324,724): raw ch0 20x20 (dead before phase E)

    const int tid = threadIdx.x;
    const int tx = tid & 15, ty = tid >> 4;
    const int bx = blockIdx.x * TILE, by = blockIdx.y * TILE;
    const int n = blockIdx.z;
    const float* cbase = cin + (size_t)n * CH * HWSZ;
    const uint8_t* pbase = pre_in + (size_t)n * HWSZ;

    // ---- hoisted coords: 20x20 raw-ch0 positions, two per thread ----
    const int lyA = tid / 20, lxA = tid % 20;
    const int gyA = by + lyA - 2, gxA = bx + lxA - 2;
    const bool okA = ((unsigned)gyA < HH) && ((unsigned)gxA < WW);
    const int offA = gyA * WW + gxA;

    const int rB = tid + 256;                  // valid when tid < 144
    const int lyB = rB / 20, lxB = rB % 20;
    const int gyB = by + lyB - 2, gxB = bx + lxB - 2;
    const bool okB = ((unsigned)gyB < HH) && ((unsigned)gxB < WW);
    const int offB = gyB * WW + gxB;

    // ---- hoisted coords: 18x18 positions, two per thread ----
    const int j0 = tid;
    const int jy0 = j0 / 18, jx0 = j0 % 18;
    const int gy0 = by + jy0 - 1, gx0 = bx + jx0 - 1;
    const bool ok0 = ((unsigned)gy0 < HH) && ((unsigned)gx0 < WW);
    const int goff0 = gy0 * WW + gx0;
    const int lpos0 = (jy0 + 1) * LW + (jx0 + 1);   // in 20x20 raw buffer
    const int cpos0 = jy0 * 18 + jx0;               // in 18x18 planes

    const int j1 = tid + 256;                  // valid when tid < 68
    const int jy1 = j1 / 18, jx1 = j1 % 18;
    const int gy1 = by + jy1 - 1, gx1 = bx + jx1 - 1;
    const bool ok1 = ((unsigned)gy1 < HH) && ((unsigned)gx1 < WW);
    const int goff1 = gy1 * WW + gx1;
    const int lpos1 = (jy1 + 1) * LW + (jx1 + 1);
    const int cpos1 = jy1 * 18 + jx1;

    // ---- A: stage raw ch0 (20x20, zero-fill OOB); zero the shared k-pad block ----
    cs20[tid < 400 ? tid : 0] = (tid < 400) ? (okA ? cbase[offA] : 0.0f) : cs20[0];
    if (tid < 144) cs20[rB] = okB ? cbase[offB] : 0.0f;
    if (tid < 8) cp[CH * CPS + tid] = 0.0f;        // zero block for B k=48..63
    __syncthreads();

    // ---- B: gate mask over 18x18 (post from raw ch0, pre bits from global) ----
    {
        float pm = -1e30f;
#pragma unroll
        for (int dy = -1; dy <= 1; ++dy)
#pragma unroll
            for (int dx = -1; dx <= 1; ++dx)
                pm = fmaxf(pm, cs20[lpos0 + dy * LW + dx]);
        float mval = 1.0f;
        if (gate) {
            int pv = ok0 ? pbase[goff0] : 0;
            mval = (pv && pm > THR) ? 1.0f : 0.0f;
        }
        gmf[j0] = mval;
    }
    if (tid < 68) {
        float pm = -1e30f;
#pragma unroll
        for (int dy = -1; dy <= 1; ++dy)
#pragma unroll
            for (int dx = -1; dx <= 1; ++dx)
                pm = fmaxf(pm, cs20[lpos1 + dy * LW + dx]);
        float mval = 1.0f;
        if (gate) {
            int pv = ok1 ? pbase[goff1] : 0;
            mval = (pv && pm > THR) ? 1.0f : 0.0f;
        }
        gmf[j1] = mval;
    }
    __syncthreads();

    // ---- C: build gated 18x18x16ch planes (gate folded into the load) ----
    {
        const float g = gmf[j0];
        cp[0 * CPS + cpos0] = cs20[lpos0] * g;
        const float* gp = cbase + goff0;
#pragma unroll
        for (int c = 1; c < CH; ++c)
            cp[c * CPS + cpos0] = (ok0 ? gp[c * HWSZ] : 0.0f) * g;
    }
    if (tid < 68) {
        const float g = gmf[j1];
        cp[0 * CPS + cpos1] = cs20[lpos1] * g;
        const float* gp = cbase + goff1;
#pragma unroll
        for (int c = 1; c < CH; ++c)
            cp[c * CPS + cpos1] = (ok1 ? gp[c * HWSZ] : 0.0f) * g;
    }
    __syncthreads();
    // gm/cs20 dead from here; phase E overwrites their region (wave-0 B-buffer)

    // ---- D: pre(i) bits from gated ch0 ----
    {
        const int db = (ty + 1) * 18 + (tx + 1);
        float pm = -1e30f;
#pragma unroll
        for (int dy = -1; dy <= 1; ++dy)
#pragma unroll
            for (int dx = -1; dx <= 1; ++dx)
                pm = fmaxf(pm, cp[db + dy * 18 + dx]);
        pre_out[(size_t)n * HWSZ + (size_t)(by + ty) * WW + (bx + tx)] = (pm > THR) ? 1 : 0;
    }

    // ---- E: rotated MFMA tile loop ----
    const int lane = tid & 63;
    const int px = lane & 15;       // B-row / D-column (pixel in tile row)
    const int q  = lane >> 4;       // quad
    const int wv = tid >> 6;        // wave in block
    unsigned int* phw = ph + wv * PHWAVE;
    const int pxw = px * PHROW + 2 * q;              // row base + lane word offset
    const unsigned* bs0 = phw + 0 * PHPLANE + px * PHROW;
    const unsigned* bs1 = phw + 1 * PHPLANE + px * PHROW;
    const unsigned* bs2 = phw + 2 * PHPLANE + px * PHROW;
    const unsigned* zbl = (const unsigned*)(cp + CH * CPS) + 4 * (q & 1);

    // held w1 split-1 A-frags (6 frags = 24 VGPR)
    frag a1h00 = *(const frag*)(w1s + (0 * 16 + px) * 64 +  0 + q * 8);
    frag a1h01 = *(const frag*)(w1s + (0 * 16 + px) * 64 + 32 + q * 8);
    frag a1h10 = *(const frag*)(w1s + (1 * 16 + px) * 64 +  0 + q * 8);
    frag a1h11 = *(const frag*)(w1s + (1 * 16 + px) * 64 + 32 + q * 8);
    frag a1h20 = *(const frag*)(w1s + (2 * 16 + px) * 64 +  0 + q * 8);
    frag a1h21 = *(const frag*)(w1s + (2 * 16 + px) * 64 + 32 + q * 8);

    float* obase = cout + (size_t)n * CH * HWSZ;

    u32x2 p1c, p2c, p3c, p1x, p2x, p3x, p1y, p2y, p3y;   // publish payload (18 u32)
    MAKEPAYLOAD(4 * wv);                                  // preamble: tile 0's perception

#pragma unroll 1
    for (int t = 0; t < 4; ++t) {
        const int rloc = 4 * wv + t;

        // publish payload (9 ds_write_b64; k=0..47, no pad writes)
        *(u32x2*)(phw + 0 * PHPLANE + pxw +  0) = p1c;
        *(u32x2*)(phw + 0 * PHPLANE + pxw +  8) = p1x;
        *(u32x2*)(phw + 0 * PHPLANE + pxw + 16) = p1y;
        *(u32x2*)(phw + 1 * PHPLANE + pxw +  0) = p2c;
        *(u32x2*)(phw + 1 * PHPLANE + pxw +  8) = p2x;
        *(u32x2*)(phw + 1 * PHPLANE + pxw + 16) = p2y;
        *(u32x2*)(phw + 2 * PHPLANE + pxw +  0) = p3c;
        *(u32x2*)(phw + 2 * PHPLANE + pxw +  8) = p3x;
        *(u32x2*)(phw + 2 * PHPLANE + pxw + 16) = p3y;
        MEMFENCE;   // publish before B-frag loads

        // layer 1: H[48 x 16px] = W1 * P
        frag b10 = bfrag_kc0(bs0, q), b20 = bfrag_kc0(bs1, q), b30 = bfrag_kc0(bs2, q);
        frag b11 = bfrag_kc1(bs0, zbl, q), b21 = bfrag_kc1(bs1, zbl, q), b31 = bfrag_kc1(bs2, zbl, q);
        f32x4 zz = { 0, 0, 0, 0 };
        f32x4 c1a0 = zz, c1b0 = zz, c1a1 = zz, c1b1 = zz, c1a2 = zz, c1b2 = zz;
        L1OT(0, a1h00, a1h01, c1a0, c1b0);
        L1OT(1, a1h10, a1h11, c1a1, c1b1);
        L1OT(2, a1h20, a1h21, c1a2, c1b2);
        MEMFENCE;   // P-frag loads complete before H overwrite

        HWB(0, c1a0, c1b0);
        HWB(1, c1a1, c1b1);
        HWB(2, c1a2, c1b2);
        MEMFENCE;   // H stores before layer-2 B-frag loads

        // next tile's perception overlaps layer-2 (reads cp only — no hazard)
        if (t < 3) { MAKEPAYLOAD(rloc + 1); }

        // layer 2: cur = W2 * relu(H) + cell
        frag h10 = bfrag_kc0(bs0, q), h20 = bfrag_kc0(bs1, q), h30 = bfrag_kc0(bs2, q);
        frag h11 = bfrag_kc1(bs0, zbl, q), h21 = bfrag_kc1(bs1, zbl, q), h31 = bfrag_kc1(bs2, zbl, q);
        frag wa10 = *(const frag*)(w2s +    0 + px * 64 +  0 + q * 8);
        frag wa20 = *(const frag*)(w2s + 1024 + px * 64 +  0 + q * 8);
        frag wa30 = *(const frag*)(w2s + 2048 + px * 64 +  0 + q * 8);
        frag wa11 = *(const frag*)(w2s +    0 + px * 64 + 32 + q * 8);
        frag wa21 = *(const frag*)(w2s + 1024 + px * 64 + 32 + q * 8);
        frag wa31 = *(const frag*)(w2s + 2048 + px * 64 + 32 + q * 8);
        const int rpos = (rloc + 1) * 18 + px + 1;
        f32x4 c2a, c2b = zz;
        c2a.x = cp[(4 * q + 0) * CPS + rpos];   // residual = gated cell
        c2a.y = cp[(4 * q + 1) * CPS + rpos];
        c2a.z = cp[(4 * q + 2) * CPS + rpos];
        c2a.w = cp[(4 * q + 3) * CPS + rpos];
        c2a = MFMA16(wa10, h10, c2a); c2a = MFMA16(wa10, h20, c2a);
        c2a = MFMA16(wa20, h10, c2a); c2a = MFMA16(wa10, h30, c2a);
        c2a = MFMA16(wa20, h20, c2a); c2a = MFMA16(wa30, h10, c2a);
        c2b = MFMA16(wa11, h11, c2b); c2b = MFMA16(wa11, h21, c2b);
        c2b = MFMA16(wa21, h11, c2b); c2b = MFMA16(wa11, h31, c2b);
        c2b = MFMA16(wa21, h21, c2b); c2b = MFMA16(wa31, h11, c2b);
        MEMFENCE;   // layer-2 H loads before next tile's publish (WAR)

        f32x4 c2 = c2a + c2b;
        float* ob = obase + (size_t)(by + rloc) * WW + bx + px;
        ob[(size_t)(4 * q + 0) * HWSZ] = c2.x;
        ob[(size_t)(4 * q + 1) * HWSZ] = c2.y;
        ob[(size_t)(4 * q + 2) * HWSZ] = c2.z;
        ob[(size_t)(4 * q + 3) * HWSZ] = c2.w;
    }
}

// ---------------- final: apply gate(30), emit channels 1..10 ----------------
__global__ __launch_bounds__(256) void final_kernel(
    const float* __restrict__ cur, const uint8_t* __restrict__ pre,
    float* __restrict__ out) {
    int i = blockIdx.x * 256 + threadIdx.x;
    if (i >= NIMG * HWSZ) return;
    int x = i % WW, y = (i / WW) % HH, n = i / HWSZ;
    const float* c0 = cur + (size_t)n * CH * HWSZ;
    float pm = -1e30f;
    for (int dy = -1; dy <= 1; ++dy) {
        int yy = y + dy;
        if ((unsigned)yy >= HH) continue;
        for (int dx = -1; dx <= 1; ++dx) {
            int xx = x + dx;
            if ((unsigned)xx >= WW) continue;
            pm = fmaxf(pm, c0[yy * WW + xx]);
        }
    }
    const bool alive = pre[i] && (pm > THR);
    float* ob = out + (size_t)n * 10 * HWSZ + y * WW + x;
#pragma unroll
    for (int k = 1; k <= 10; ++k)
        ob[(k - 1) * HWSZ] = alive ? c0[k * HWSZ + y * WW + x] : 0.0f;
}

extern "C" void kernel_launch(void* const* d_in, const int* in_sizes, int n_in,
                              void* d_out, int out_size, void* d_ws, size_t ws_size,
                              hipStream_t stream) {
    const float* inp = (const float*)d_in[0];
    const float* w1  = (const float*)d_in[1];
    const float* w2  = (const float*)d_in[2];
    float* out = (float*)d_out;

    const size_t SE = (size_t)NIMG * CH * HWSZ;    // 8,388,608 floats
    float* bufA = (float*)d_ws;
    float* bufB = bufA + SE;
    uint8_t* bitsA = (uint8_t*)(bufB + SE);
    uint8_t* bitsB = bitsA + (size_t)NIMG * HWSZ;
    unsigned short* w1s = (unsigned short*)(bitsB + (size_t)NIMG * HWSZ); // [3][48][64]
    unsigned short* w2s = w1s + 3 * 48 * 64;                              // [3][16][64]

    init_kernel<<<((int)SE + 255) / 256, 256, 0, stream>>>(inp, bufA);
    prep_weights<<<16, 256, 0, stream>>>(w1, w2, w1s, w2s);

    dim3 grid(WW / TILE, HH / TILE, NIMG);
    float* src = bufA;
    float* dst = bufB;
    uint8_t* pin = bitsB;   // unused on first iter (gate=0)
    uint8_t* pout = bitsA;
    for (int it = 0; it < NUM_ITER; ++it) {
        step_kernel<<<grid, 256, 0, stream>>>(src, dst, pin, pout, w1s, w2s,
                                              it == 0 ? 0 : 1);
        float* t = src; src = dst; dst = t;
        uint8_t* tb = pin; pin = pout; pout = tb;
    }
    // after loop: src = cur(30), pin = pre(30) bits
    final_kernel<<<(NIMG * HWSZ + 255) / 256, 256, 0, stream>>>(src, pin, out);
}